// Round 13
// baseline (257.215 us; speedup 1.0000x reference)
//
#include <hip/hip_runtime.h>
#include <hip/hip_bf16.h>

// Encoder: B=4, S=2048, D=256, H=8, DK=32, DFF=1024, fp32 in/out.
// bf16 pipeline. Fixed-base softmax (scores>=0: ReLU'd q,k), l via
// ones-MFMA. Attn: ZERO-LDS, ZERO-barrier — MFMA fragments loaded
// directly from L2-resident K / V^T with 2-deep register prefetch;
// normalize fused in epilogue. GEMM: 64x64/4-wave dbuf (unchanged).

#define MROWS 8192   // B*S
#define DMODEL 256
#define SEQ 2048
#define LN_EPS 1e-5f

typedef float f32x4 __attribute__((ext_vector_type(4)));
typedef unsigned int u32x4 __attribute__((ext_vector_type(4)));

__device__ __forceinline__ unsigned pk2(float lo, float hi) {
  union { __hip_bfloat162 h; unsigned u; } c;
  c.h = __float22bfloat162_rn(make_float2(lo, hi));
  return c.u;
}
__device__ __forceinline__ unsigned short bf1(float f) {
  union { __hip_bfloat16 h; unsigned short u; } c;
  c.h = __float2bfloat16(f);
  return c.u;
}

__device__ __forceinline__ f32x4 mfma_bf16(u32x4 a, u32x4 b, f32x4 c) {
  asm volatile("v_mfma_f32_16x16x32_bf16 %0, %1, %2, %0"
               : "+v"(c) : "v"(a), "v"(b));
  return c;
}

__device__ __forceinline__ void gload_lds16(const void* g, void* l) {
  __builtin_amdgcn_global_load_lds(
      (const __attribute__((address_space(1))) void*)g,
      (__attribute__((address_space(3))) void*)l, 16, 0, 0);
}

// ---------------- fp32 -> bf16 batch convert ----------------
struct CvtArgs {
  const float* s[13];
  unsigned short* d[13];
  int n4[13];
};
__global__ __launch_bounds__(256) void cvt_kernel(CvtArgs a) {
  const int y = blockIdx.y;
  const int n4 = a.n4[y];
  const float4* src = (const float4*)a.s[y];
  unsigned short* dst = a.d[y];
  for (int i = blockIdx.x * 256 + threadIdx.x; i < n4; i += 256 * 256) {
    float4 v = src[i];
    uint2 o;
    o.x = pk2(v.x, v.y);
    o.y = pk2(v.z, v.w);
    *(uint2*)(dst + (size_t)i * 4) = o;
  }
}

// ---------------- bf16 MFMA GEMM: relu(A @ W^T) (+res) ----------------
// 256 threads, 4 waves (2x2), block 64x64, wave 32x32, BK=64, double-buffer
// LDS staged via global_load_lds (linear dest, pre-swizzled source).
// Fused-QKV epilogue: n0<256 -> outB (bscale), [256,512) -> outB2,
// >=512 -> outVT (V^T [b*8+h][d][s]). XCD-swizzled 1D grid.
__global__ __launch_bounds__(256) void gemm_bf16_kernel(
    const unsigned short* __restrict__ A, const unsigned short* __restrict__ W,
    const float* __restrict__ res, float* __restrict__ outF,
    unsigned short* __restrict__ outB, unsigned short* __restrict__ outB2,
    unsigned short* __restrict__ outVT, float bscale, int N, int K, int ntx) {
  __shared__ alignas(16) unsigned short As[2][64 * 64];
  __shared__ alignas(16) unsigned short Ws[2][64 * 64];
  const int tid = threadIdx.x;
  const int w = tid >> 6, lane = tid & 63;
  const int lq = lane & 15, kg = lane >> 4;
  const int wm = w >> 1, wn = w & 1;
  const int nwg = gridDim.x, cpx = nwg >> 3, bid = blockIdx.x;
  const int lid = (bid & 7) * cpx + (bid >> 3);
  const int m0 = (lid / ntx) * 64, n0 = (lid % ntx) * 64;

  f32x4 acc[2][2] = {};

  auto STAGE = [&](int buf, int k0) {
#pragma unroll
    for (int i = 0; i < 2; i++) {
      const int li = i * 256 + tid;
      const int row = li >> 3, sl = (li & 7) ^ (row & 7);
      gload_lds16(A + (size_t)(m0 + row) * K + k0 + sl * 8,
                  (char*)As[buf] + (i * 256 + (tid & ~63)) * 16);
    }
#pragma unroll
    for (int i = 0; i < 2; i++) {
      const int li = i * 256 + tid;
      const int row = li >> 3, sl = (li & 7) ^ (row & 7);
      gload_lds16(W + (size_t)(n0 + row) * K + k0 + sl * 8,
                  (char*)Ws[buf] + (i * 256 + (tid & ~63)) * 16);
    }
  };

  const int nt = K >> 6;
  STAGE(0, 0);
  for (int t = 0; t < nt; t++) {
    __syncthreads();  // drains vmcnt: buf[t&1] ready
    if (t + 1 < nt) STAGE((t + 1) & 1, (t + 1) << 6);
    const unsigned short* as = As[t & 1];
    const unsigned short* wsb = Ws[t & 1];
#pragma unroll
    for (int kk = 0; kk < 2; kk++) {
      const int sl = (((kk * 4 + kg) ^ (lq & 7)) << 3);
      u32x4 a0 = *(const u32x4*)&as[((wm * 32 + lq) << 6) + sl];
      u32x4 a1 = *(const u32x4*)&as[((wm * 32 + 16 + lq) << 6) + sl];
      u32x4 b0 = *(const u32x4*)&wsb[((wn * 32 + lq) << 6) + sl];
      u32x4 b1 = *(const u32x4*)&wsb[((wn * 32 + 16 + lq) << 6) + sl];
      __builtin_amdgcn_s_setprio(1);
      acc[0][0] = mfma_bf16(a0, b0, acc[0][0]);
      acc[0][1] = mfma_bf16(a0, b1, acc[0][1]);
      acc[1][0] = mfma_bf16(a1, b0, acc[1][0]);
      acc[1][1] = mfma_bf16(a1, b1, acc[1][1]);
      __builtin_amdgcn_s_setprio(0);
    }
  }

  // Epilogue: D row = kg*4+r, col = lq per 16x16 frag.
  if (outVT && n0 >= 512) {  // V^T path (fused QKV)
#pragma unroll
    for (int mi = 0; mi < 2; mi++) {
      const int mb = m0 + wm * 32 + mi * 16 + kg * 4;
      const int bq = mb >> 11, s0 = mb & 2047;
#pragma unroll
      for (int nj = 0; nj < 2; nj++) {
        const int nn = n0 - 512 + wn * 32 + nj * 16 + lq;
        const int hh = nn >> 5, dd = nn & 31;
        uint2 pv;
        pv.x = pk2(fmaxf(acc[mi][nj][0], 0.f), fmaxf(acc[mi][nj][1], 0.f));
        pv.y = pk2(fmaxf(acc[mi][nj][2], 0.f), fmaxf(acc[mi][nj][3], 0.f));
        *(uint2*)(outVT + ((size_t)(bq * 8 + hh) * 32 + dd) * 2048 + s0) = pv;
      }
    }
  } else if (outB2 && n0 >= 256) {  // K path (fused QKV)
#pragma unroll
    for (int mi = 0; mi < 2; mi++) {
      const int m = m0 + wm * 32 + mi * 16 + kg * 4;
#pragma unroll
      for (int nj = 0; nj < 2; nj++) {
        const int nn = n0 - 256 + wn * 32 + nj * 16 + lq;
#pragma unroll
        for (int r = 0; r < 4; r++)
          outB2[(size_t)(m + r) * 256 + nn] = bf1(fmaxf(acc[mi][nj][r], 0.f));
      }
    }
  } else {
    const int ldo = (outB2 || outVT) ? 256 : N;  // fused-Q path uses 256
#pragma unroll
    for (int mi = 0; mi < 2; mi++) {
      const int m = m0 + wm * 32 + mi * 16 + kg * 4;
#pragma unroll
      for (int nj = 0; nj < 2; nj++) {
        const int n = n0 + wn * 32 + nj * 16 + lq;
#pragma unroll
        for (int r = 0; r < 4; r++) {
          float v = fmaxf(acc[mi][nj][r], 0.f);
          if (res) v += res[(size_t)(m + r) * N + n];
          if (outF) outF[(size_t)(m + r) * N + n] = v;
          if (outB) outB[(size_t)(m + r) * ldo + n] = bf1(v * bscale);
        }
      }
    }
  }
}

// ---------------- MFMA flash attention: zero-LDS, zero-barrier ----------
// 4 independent waves/block, 32 q rows each (2 q-frags), 64 keys/iter.
// Fragments read DIRECTLY from global (L2-resident K, V^T); permuted-K
// QK^T (R11) so P feeds PV in-register; fixed-base softmax; l via
// ones-MFMA; normalize + bf16 write in epilogue. 2-deep reg prefetch.
__global__ __launch_bounds__(256) void attn_mfma_kernel(
    const unsigned short* __restrict__ Q, const unsigned short* __restrict__ K,
    const unsigned short* __restrict__ VT, unsigned short* __restrict__ O) {
  const int tid = threadIdx.x;
  const int w = tid >> 6;
  const int lane = tid & 63;
  const int lq = lane & 15;
  const int kg = lane >> 4;
  // 1D chunked-bijection swizzle: XCD gets 64 consecutive lids = 4 heads.
  const int bid = blockIdx.x;                // 0..511
  const int lid = (bid & 7) * 64 + (bid >> 3);
  const int bh = lid >> 4, qt = lid & 15;    // 16 blocks per bh
  const int b = bh >> 3, h = bh & 7;
  const int q0 = qt * 128 + w * 32;
  const size_t base = (size_t)b * SEQ * DMODEL + h * 32;
  const unsigned short* vtb = VT + (size_t)bh * 32 * 2048;

  u32x4 qf[2];
  qf[0] = *(const u32x4*)(Q + base + (size_t)(q0 + lq) * DMODEL + kg * 8);
  qf[1] = *(const u32x4*)(Q + base + (size_t)(q0 + 16 + lq) * DMODEL + kg * 8);

  f32x4 oLo[2] = {{0.f, 0.f, 0.f, 0.f}, {0.f, 0.f, 0.f, 0.f}};
  f32x4 oHi[2] = {{0.f, 0.f, 0.f, 0.f}, {0.f, 0.f, 0.f, 0.f}};
  f32x4 lac[2] = {{0.f, 0.f, 0.f, 0.f}, {0.f, 0.f, 0.f, 0.f}};
  const unsigned ONE2 = 0x3F803F80u;
  const u32x4 ones = {ONE2, ONE2, ONE2, ONE2};

  // Loop-invariant per-lane base pointers.
  // ka[s4]: K row krow[s4] (permuted so PV B assembles in-register), col kg*8.
  const unsigned short* kp[4];
#pragma unroll
  for (int s4 = 0; s4 < 4; s4++) {
    const int krow =
        (s4 >> 1) * 32 + ((lq >> 2) << 3) + ((s4 & 1) << 2) + (lq & 3);
    kp[s4] = K + base + (size_t)krow * DMODEL + kg * 8;
  }
  // va: vt rows lq / 16+lq, key cols kg*8 and 32+kg*8 (+kt per iter).
  const unsigned short* vp0 = vtb + (size_t)lq * 2048 + kg * 8;
  const unsigned short* vp1 = vtb + (size_t)(16 + lq) * 2048 + kg * 8;

  auto LOAD = [&](u32x4 (&ka)[4], u32x4 (&va)[4], int kt) {
#pragma unroll
    for (int s4 = 0; s4 < 4; s4++)
      ka[s4] = *(const u32x4*)(kp[s4] + (size_t)kt * DMODEL);
    va[0] = *(const u32x4*)(vp0 + kt);
    va[1] = *(const u32x4*)(vp0 + kt + 32);
    va[2] = *(const u32x4*)(vp1 + kt);
    va[3] = *(const u32x4*)(vp1 + kt + 32);
  };

  auto COMPUTE = [&](const u32x4 (&ka)[4], const u32x4 (&va)[4]) {
    f32x4 sc[2][4];
    __builtin_amdgcn_s_setprio(1);
#pragma unroll
    for (int f = 0; f < 2; f++)
#pragma unroll
      for (int s4 = 0; s4 < 4; s4++) {
        f32x4 z = {0.f, 0.f, 0.f, 0.f};
        sc[f][s4] = mfma_bf16(ka[s4], qf[f], z);
      }
    __builtin_amdgcn_s_setprio(0);
    // P = exp2(sc) (sc >= 0; base cancels in o/l) -> in-register B operands
    u32x4 pf0[2], pf1[2];
#pragma unroll
    for (int f = 0; f < 2; f++) {
      pf0[f][0] = pk2(exp2f(sc[f][0][0]), exp2f(sc[f][0][1]));
      pf0[f][1] = pk2(exp2f(sc[f][0][2]), exp2f(sc[f][0][3]));
      pf0[f][2] = pk2(exp2f(sc[f][1][0]), exp2f(sc[f][1][1]));
      pf0[f][3] = pk2(exp2f(sc[f][1][2]), exp2f(sc[f][1][3]));
      pf1[f][0] = pk2(exp2f(sc[f][2][0]), exp2f(sc[f][2][1]));
      pf1[f][1] = pk2(exp2f(sc[f][2][2]), exp2f(sc[f][2][3]));
      pf1[f][2] = pk2(exp2f(sc[f][3][0]), exp2f(sc[f][3][1]));
      pf1[f][3] = pk2(exp2f(sc[f][3][2]), exp2f(sc[f][3][3]));
    }
#pragma unroll
    for (int f = 0; f < 2; f++) {
      __builtin_amdgcn_s_setprio(1);
      oLo[f] = mfma_bf16(va[0], pf0[f], oLo[f]);
      oLo[f] = mfma_bf16(va[1], pf1[f], oLo[f]);
      oHi[f] = mfma_bf16(va[2], pf0[f], oHi[f]);
      oHi[f] = mfma_bf16(va[3], pf1[f], oHi[f]);
      lac[f] = mfma_bf16(ones, pf0[f], lac[f]);
      lac[f] = mfma_bf16(ones, pf1[f], lac[f]);
      __builtin_amdgcn_s_setprio(0);
    }
  };

  // 2-deep software pipeline with named register sets (static indexing).
  u32x4 kaA[4], vaA[4], kaB[4], vaB[4];
  LOAD(kaA, vaA, 0);
  for (int t = 0; t < 32; t += 2) {
    LOAD(kaB, vaB, (t + 1) * 64);
    COMPUTE(kaA, vaA);
    if (t + 2 < 32) LOAD(kaA, vaA, (t + 2) * 64);
    COMPUTE(kaB, vaB);
  }

  // Epilogue: normalize, write bf16 O[qrow][h*32+d].
#pragma unroll
  for (int f = 0; f < 2; f++) {
    const float inv = 1.f / lac[f][0];
    const int qrow = q0 + f * 16 + lq;
    unsigned short* op =
        O + (size_t)b * SEQ * DMODEL + (size_t)qrow * DMODEL + h * 32;
    uint2 vlo, vhi;
    vlo.x = pk2(oLo[f][0] * inv, oLo[f][1] * inv);
    vlo.y = pk2(oLo[f][2] * inv, oLo[f][3] * inv);
    vhi.x = pk2(oHi[f][0] * inv, oHi[f][1] * inv);
    vhi.y = pk2(oHi[f][2] * inv, oHi[f][3] * inv);
    *(uint2*)(op + kg * 4) = vlo;
    *(uint2*)(op + 16 + kg * 4) = vhi;
  }
}

// ---------------- LayerNorm (256) ----------------
__global__ __launch_bounds__(256) void ln_kernel(
    const float* __restrict__ X, const float* __restrict__ g,
    const float* __restrict__ b, float* __restrict__ Y,
    unsigned short* __restrict__ Yb) {
  const int wid = (blockIdx.x * blockDim.x + threadIdx.x) >> 6;
  const int lane = threadIdx.x & 63;
  const float* x = X + (size_t)wid * DMODEL;
  float4 v = *(const float4*)(x + lane * 4);
  float s = v.x + v.y + v.z + v.w;
  float s2 = v.x * v.x + v.y * v.y + v.z * v.z + v.w * v.w;
#pragma unroll
  for (int off = 32; off >= 1; off >>= 1) {
    s += __shfl_xor(s, off, 64);
    s2 += __shfl_xor(s2, off, 64);
  }
  const float mu = s * (1.f / DMODEL);
  const float var = s2 * (1.f / DMODEL) - mu * mu;
  const float inv = rsqrtf(var + LN_EPS);
  float4 gv = *(const float4*)(g + lane * 4);
  float4 bv = *(const float4*)(b + lane * 4);
  float4 o;
  o.x = (v.x - mu) * inv * gv.x + bv.x;
  o.y = (v.y - mu) * inv * gv.y + bv.y;
  o.z = (v.z - mu) * inv * gv.z + bv.z;
  o.w = (v.w - mu) * inv * gv.w + bv.w;
  if (Y) *(float4*)(Y + (size_t)wid * DMODEL + lane * 4) = o;
  if (Yb) {
    uint2 p;
    p.x = pk2(o.x, o.y);
    p.y = pk2(o.z, o.w);
    *(uint2*)(Yb + (size_t)wid * DMODEL + lane * 4) = p;
  }
}

extern "C" void kernel_launch(void* const* d_in, const int* in_sizes, int n_in,
                              void* d_out, int out_size, void* d_ws, size_t ws_size,
                              hipStream_t stream) {
  const float* x = (const float*)d_in[0];
  const float* g1 = (const float*)d_in[13];
  const float* b1 = (const float*)d_in[14];
  const float* g2 = (const float*)d_in[15];
  const float* b2 = (const float*)d_in[16];
  const float* g3 = (const float*)d_in[17];
  const float* b3 = (const float*)d_in[18];
  const float* g4 = (const float*)d_in[19];
  const float* b4 = (const float*)d_in[20];

  float* out = (float*)d_out;
  float* ws = (float*)d_ws;
  const size_t NM = (size_t)MROWS * DMODEL;
  const float QSCALE = 0.17677669529663687f * 1.4426950408889634f;

  float* F0 = ws;
  float* F1 = ws + NM;
  unsigned short* fb = (unsigned short*)(ws + 2 * NM);  // 8192x1024 bf16
  unsigned short* xb = (unsigned short*)(ws + 4 * NM);
  unsigned short* qb = xb + NM;
  unsigned short* kb = qb + NM;
  unsigned short* ob = kb + NM;
  unsigned short* nb = ob + NM;
  unsigned short* wb = nb + NM;
  unsigned short* qkv1 = wb;
  unsigned short* qkv2 = wb + 3 * 65536;
  unsigned short* o1w = wb + 6 * 65536;
  unsigned short* o2w = wb + 7 * 65536;
  unsigned short* f11 = wb + 8 * 65536;
  unsigned short* f21 = f11 + 262144;
  unsigned short* f12 = f21 + 262144;
  unsigned short* f22 = f12 + 262144;
  unsigned short* vt = (unsigned short*)F0;  // aliases F0 (dead then)

  {
    CvtArgs a;
    a.s[0] = x; a.d[0] = xb; a.n4[0] = (int)(NM / 4);
    unsigned short* wd[12] = {qkv1, qkv1 + 65536, qkv1 + 131072, o1w,
                              qkv2, qkv2 + 65536, qkv2 + 131072, o2w,
                              f11, f21, f12, f22};
    for (int i = 0; i < 12; i++) {
      a.s[i + 1] = (const float*)d_in[i + 1];
      a.d[i + 1] = wd[i];
      a.n4[i + 1] = (i < 8) ? 65536 / 4 : 262144 / 4;
    }
    cvt_kernel<<<dim3(256, 13), 256, 0, stream>>>(a);
  }

  auto gemm = [&](const unsigned short* A, const unsigned short* W,
                  const float* res, float* oF, unsigned short* oB,
                  unsigned short* oB2, unsigned short* oVT, float bs,
                  int N, int K) {
    const int ntx = N / 64;
    const int nwg = ntx * (MROWS / 64);
    gemm_bf16_kernel<<<nwg, 256, 0, stream>>>(A, W, res, oF, oB, oB2, oVT,
                                              bs, N, K, ntx);
  };
  auto attn = [&](const unsigned short* Q, const unsigned short* K,
                  const unsigned short* VT, unsigned short* O) {
    attn_mfma_kernel<<<512, 256, 0, stream>>>(Q, K, VT, O);
  };
  auto ln = [&](const float* X, const float* gm, const float* bt, float* Y,
                unsigned short* Yb) {
    ln_kernel<<<MROWS / 4, 256, 0, stream>>>(X, gm, bt, Y, Yb);
  };

  // ---- Block 1 ----
  gemm(xb, qkv1, nullptr, nullptr, qb, kb, vt, QSCALE, 768, 256);  // QKV
  attn(qb, kb, vt, ob);
  gemm(ob, o1w, x, F0, nullptr, nullptr, nullptr, 1.f, 256, 256);  // x1
  ln(F0, g1, b1, F1, nb);
  gemm(nb, f11, nullptr, nullptr, fb, nullptr, nullptr, 1.f, 1024, 256);
  gemm(fb, f21, F1, F0, nullptr, nullptr, nullptr, 1.f, 256, 1024);
  ln(F0, g2, b2, F1, xb);

  // ---- Block 2 ----
  gemm(xb, qkv2, nullptr, nullptr, qb, kb, vt, QSCALE, 768, 256);
  attn(qb, kb, vt, ob);
  gemm(ob, o2w, F1, F0, nullptr, nullptr, nullptr, 1.f, 256, 256);
  ln(F0, g3, b3, F1, nb);
  gemm(nb, f12, nullptr, nullptr, fb, nullptr, nullptr, 1.f, 1024, 256);
  gemm(fb, f22, F1, F0, nullptr, nullptr, nullptr, 1.f, 256, 1024);
  ln(F0, g4, b4, out, nullptr);
}

// Round 14
// 246.951 us; speedup vs baseline: 1.0416x; 1.0416x over previous
//
#include <hip/hip_runtime.h>
#include <hip/hip_bf16.h>

// Encoder: B=4, S=2048, D=256, H=8, DK=32, DFF=1024, fp32 in/out.
// bf16 pipeline. Fixed-base softmax (scores>=0: ReLU'd q,k), l via
// ones-MFMA. Attn: R11 LDS structure + triple-buffer + counted vmcnt
// (raw s_barrier, never drain to 0 mid-loop). GEMM: 64x64/4-wave dbuf;
// N=256 GEMMs split-K=2 with fused relu+add+LN combine.

#define MROWS 8192   // B*S
#define DMODEL 256
#define SEQ 2048
#define LN_EPS 1e-5f

typedef float f32x4 __attribute__((ext_vector_type(4)));
typedef unsigned int u32x4 __attribute__((ext_vector_type(4)));

__device__ __forceinline__ unsigned pk2(float lo, float hi) {
  union { __hip_bfloat162 h; unsigned u; } c;
  c.h = __float22bfloat162_rn(make_float2(lo, hi));
  return c.u;
}
__device__ __forceinline__ unsigned short bf1(float f) {
  union { __hip_bfloat16 h; unsigned short u; } c;
  c.h = __float2bfloat16(f);
  return c.u;
}

__device__ __forceinline__ f32x4 mfma_bf16(u32x4 a, u32x4 b, f32x4 c) {
  asm volatile("v_mfma_f32_16x16x32_bf16 %0, %1, %2, %0"
               : "+v"(c) : "v"(a), "v"(b));
  return c;
}

__device__ __forceinline__ void gload_lds16(const void* g, void* l) {
  __builtin_amdgcn_global_load_lds(
      (const __attribute__((address_space(1))) void*)g,
      (__attribute__((address_space(3))) void*)l, 16, 0, 0);
}

// ---------------- fp32 -> bf16 batch convert ----------------
struct CvtArgs {
  const float* s[13];
  unsigned short* d[13];
  int n4[13];
};
__global__ __launch_bounds__(256) void cvt_kernel(CvtArgs a) {
  const int y = blockIdx.y;
  const int n4 = a.n4[y];
  const float4* src = (const float4*)a.s[y];
  unsigned short* dst = a.d[y];
  for (int i = blockIdx.x * 256 + threadIdx.x; i < n4; i += 256 * 256) {
    float4 v = src[i];
    uint2 o;
    o.x = pk2(v.x, v.y);
    o.y = pk2(v.z, v.w);
    *(uint2*)(dst + (size_t)i * 4) = o;
  }
}

// ---------------- bf16 MFMA GEMM: relu(A @ W^T) (+res) ----------------
// 256 threads, 4 waves (2x2), block 64x64, wave 32x32, BK=64, dbuf.
// splitk: grid doubled, lid&1 = K-slice, raw fp32 partial -> outP0/P1.
// Fused-QKV epilogue: n0<256 -> outB (bscale), [256,512) -> outB2,
// >=512 -> outVT (V^T [b*8+h][d][s]). XCD-swizzled 1D grid.
__global__ __launch_bounds__(256) void gemm_bf16_kernel(
    const unsigned short* __restrict__ A, const unsigned short* __restrict__ W,
    const float* __restrict__ res, float* __restrict__ outF,
    unsigned short* __restrict__ outB, unsigned short* __restrict__ outB2,
    unsigned short* __restrict__ outVT, float* __restrict__ outP0,
    float* __restrict__ outP1, float bscale, int N, int K, int ntx,
    int splitk) {
  __shared__ alignas(16) unsigned short As[2][64 * 64];
  __shared__ alignas(16) unsigned short Ws[2][64 * 64];
  const int tid = threadIdx.x;
  const int w = tid >> 6, lane = tid & 63;
  const int lq = lane & 15, kg = lane >> 4;
  const int wm = w >> 1, wn = w & 1;
  const int nwg = gridDim.x, cpx = nwg >> 3, bid = blockIdx.x;
  int lid = (bid & 7) * cpx + (bid >> 3);
  int kslice = 0;
  if (splitk) { kslice = lid & 1; lid >>= 1; }
  const int m0 = (lid / ntx) * 64, n0 = (lid % ntx) * 64;
  const int klen = splitk ? (K >> 1) : K;
  const unsigned short* Ab = A + (size_t)kslice * (K >> 1);
  const unsigned short* Wb = W + (size_t)kslice * (K >> 1);

  f32x4 acc[2][2] = {};

  auto STAGE = [&](int buf, int k0) {
#pragma unroll
    for (int i = 0; i < 2; i++) {
      const int li = i * 256 + tid;
      const int row = li >> 3, sl = (li & 7) ^ (row & 7);
      gload_lds16(Ab + (size_t)(m0 + row) * K + k0 + sl * 8,
                  (char*)As[buf] + (i * 256 + (tid & ~63)) * 16);
    }
#pragma unroll
    for (int i = 0; i < 2; i++) {
      const int li = i * 256 + tid;
      const int row = li >> 3, sl = (li & 7) ^ (row & 7);
      gload_lds16(Wb + (size_t)(n0 + row) * K + k0 + sl * 8,
                  (char*)Ws[buf] + (i * 256 + (tid & ~63)) * 16);
    }
  };

  const int nt = klen >> 6;
  STAGE(0, 0);
  for (int t = 0; t < nt; t++) {
    __syncthreads();  // drains vmcnt: buf[t&1] ready
    if (t + 1 < nt) STAGE((t + 1) & 1, (t + 1) << 6);
    const unsigned short* as = As[t & 1];
    const unsigned short* wsb = Ws[t & 1];
#pragma unroll
    for (int kk = 0; kk < 2; kk++) {
      const int sl = (((kk * 4 + kg) ^ (lq & 7)) << 3);
      u32x4 a0 = *(const u32x4*)&as[((wm * 32 + lq) << 6) + sl];
      u32x4 a1 = *(const u32x4*)&as[((wm * 32 + 16 + lq) << 6) + sl];
      u32x4 b0 = *(const u32x4*)&wsb[((wn * 32 + lq) << 6) + sl];
      u32x4 b1 = *(const u32x4*)&wsb[((wn * 32 + 16 + lq) << 6) + sl];
      __builtin_amdgcn_s_setprio(1);
      acc[0][0] = mfma_bf16(a0, b0, acc[0][0]);
      acc[0][1] = mfma_bf16(a0, b1, acc[0][1]);
      acc[1][0] = mfma_bf16(a1, b0, acc[1][0]);
      acc[1][1] = mfma_bf16(a1, b1, acc[1][1]);
      __builtin_amdgcn_s_setprio(0);
    }
  }

  // Epilogue: D row = kg*4+r, col = lq per 16x16 frag.
  if (splitk) {  // raw fp32 partial (no relu, no res)
    float* P = kslice ? outP1 : outP0;
#pragma unroll
    for (int mi = 0; mi < 2; mi++) {
      const int m = m0 + wm * 32 + mi * 16 + kg * 4;
#pragma unroll
      for (int nj = 0; nj < 2; nj++) {
        const int n = n0 + wn * 32 + nj * 16 + lq;
#pragma unroll
        for (int r = 0; r < 4; r++)
          P[(size_t)(m + r) * N + n] = acc[mi][nj][r];
      }
    }
  } else if (outVT && n0 >= 512) {  // V^T path (fused QKV)
#pragma unroll
    for (int mi = 0; mi < 2; mi++) {
      const int mb = m0 + wm * 32 + mi * 16 + kg * 4;
      const int bq = mb >> 11, s0 = mb & 2047;
#pragma unroll
      for (int nj = 0; nj < 2; nj++) {
        const int nn = n0 - 512 + wn * 32 + nj * 16 + lq;
        const int hh = nn >> 5, dd = nn & 31;
        uint2 pv;
        pv.x = pk2(fmaxf(acc[mi][nj][0], 0.f), fmaxf(acc[mi][nj][1], 0.f));
        pv.y = pk2(fmaxf(acc[mi][nj][2], 0.f), fmaxf(acc[mi][nj][3], 0.f));
        *(uint2*)(outVT + ((size_t)(bq * 8 + hh) * 32 + dd) * 2048 + s0) = pv;
      }
    }
  } else if (outB2 && n0 >= 256) {  // K path (fused QKV)
#pragma unroll
    for (int mi = 0; mi < 2; mi++) {
      const int m = m0 + wm * 32 + mi * 16 + kg * 4;
#pragma unroll
      for (int nj = 0; nj < 2; nj++) {
        const int nn = n0 - 256 + wn * 32 + nj * 16 + lq;
#pragma unroll
        for (int r = 0; r < 4; r++)
          outB2[(size_t)(m + r) * 256 + nn] = bf1(fmaxf(acc[mi][nj][r], 0.f));
      }
    }
  } else {
    const int ldo = (outB2 || outVT) ? 256 : N;  // fused-Q path uses 256
#pragma unroll
    for (int mi = 0; mi < 2; mi++) {
      const int m = m0 + wm * 32 + mi * 16 + kg * 4;
#pragma unroll
      for (int nj = 0; nj < 2; nj++) {
        const int n = n0 + wn * 32 + nj * 16 + lq;
#pragma unroll
        for (int r = 0; r < 4; r++) {
          float v = fmaxf(acc[mi][nj][r], 0.f);
          if (res) v += res[(size_t)(m + r) * N + n];
          if (outF) outF[(size_t)(m + r) * N + n] = v;
          if (outB) outB[(size_t)(m + r) * ldo + n] = bf1(v * bscale);
        }
      }
    }
  }
}

// ---------------- MFMA flash attention, fixed-base softmax ----------------
// 4 waves x 32 q rows (2 q-frags), 64 keys/step, TRIPLE-buffered K/V with
// counted vmcnt (each wave: 2 gload_lds per stage, 2 stages in flight,
// s_waitcnt vmcnt(2) + raw s_barrier; vmcnt(0) only on the last tile).
// Race-safety: buffer reuse distance 3; barrier(t) happens after all waves
// completed compute(t-1) (program order), and STAGE(t+2) [after barrier(t)]
// overwrites the buffer last read at compute(t-1).
// Permuted-K QK^T (P feeds PV in-register), KV-split2, fp32 partials.
__global__ __launch_bounds__(256) void attn_mfma_kernel(
    const unsigned short* __restrict__ Q, const unsigned short* __restrict__ K,
    const unsigned short* __restrict__ VT, float* __restrict__ oP,
    float* __restrict__ lP, int nkeys) {
  __shared__ alignas(16) unsigned short Ks[3][64 * 32];  // [key][4 slots x 8]
  __shared__ alignas(16) unsigned short Vt[3][32 * 64];  // [d][8 slots x 8]

  const int tid = threadIdx.x;
  const int w = tid >> 6;
  const int lane = tid & 63;
  const int lq = lane & 15;
  const int kg = lane >> 4;
  const int bh = blockIdx.y, b = bh >> 3, h = bh & 7;
  const int p = blockIdx.z;
  const int q0 = blockIdx.x * 128 + w * 32;
  const size_t base = (size_t)b * SEQ * DMODEL + h * 32;

  u32x4 qf[2];
  qf[0] = *(const u32x4*)(Q + base + (size_t)(q0 + lq) * DMODEL + kg * 8);
  qf[1] = *(const u32x4*)(Q + base + (size_t)(q0 + 16 + lq) * DMODEL + kg * 8);

  f32x4 oLo[2] = {{0.f, 0.f, 0.f, 0.f}, {0.f, 0.f, 0.f, 0.f}};
  f32x4 oHi[2] = {{0.f, 0.f, 0.f, 0.f}, {0.f, 0.f, 0.f, 0.f}};
  f32x4 lac[2] = {{0.f, 0.f, 0.f, 0.f}, {0.f, 0.f, 0.f, 0.f}};
  const unsigned ONE2 = 0x3F803F80u;
  const u32x4 ones = {ONE2, ONE2, ONE2, ONE2};

  const int kg4 = (lane & 3) ^ ((lane >> 3) & 3);  // K src slot swizzle
  const int vg8 = (lane & 7) ^ (lane >> 3);        // V src slot swizzle
  const unsigned short* vtb = VT + (size_t)bh * 32 * 2048;
  const int vslot = lq & 7;

  // Permuted ka rows (R11): PV B-operand assembles in-register.
  int krow[4], kslt[4];
#pragma unroll
  for (int s4 = 0; s4 < 4; s4++) {
    const int g = (s4 >> 1) * 32 + ((lq >> 2) << 3) + ((s4 & 1) << 2) + (lq & 3);
    krow[s4] = g;
    kslt[s4] = kg ^ ((g >> 1) & 3);
  }

  auto STAGE = [&](int buf, int kt) {
    const int kr = w * 16 + (lane >> 2);
    gload_lds16(K + base + (size_t)(kt + kr) * DMODEL + kg4 * 8,
                (char*)Ks[buf] + w * 1024);
    const int d = w * 8 + (lane >> 3);
    gload_lds16(vtb + (size_t)d * 2048 + kt + vg8 * 8,
                (char*)Vt[buf] + w * 1024);
  };

  const int kbeg = p * nkeys;
  const int nt = nkeys >> 6;  // 16
  STAGE(0, kbeg);
  STAGE(1, kbeg + 64);
  int cb = 0;
  for (int t = 0; t < nt; t++) {
    if (t + 1 < nt)
      asm volatile("s_waitcnt vmcnt(2)" ::: "memory");
    else
      asm volatile("s_waitcnt vmcnt(0)" ::: "memory");
    __builtin_amdgcn_s_barrier();
    if (t + 2 < nt) {
      int sb = cb + 2; if (sb >= 3) sb -= 3;
      STAGE(sb, kbeg + (t + 2) * 64);
    }
    const unsigned short* ks = &Ks[cb][0];
    const unsigned short* vs = &Vt[cb][0];

    u32x4 ka[4];
#pragma unroll
    for (int s4 = 0; s4 < 4; s4++)
      ka[s4] = *(const u32x4*)&ks[(krow[s4] << 5) + (kslt[s4] << 3)];

    f32x4 sc[2][4];
    __builtin_amdgcn_s_setprio(1);
#pragma unroll
    for (int f = 0; f < 2; f++)
#pragma unroll
      for (int s4 = 0; s4 < 4; s4++) {
        f32x4 z = {0.f, 0.f, 0.f, 0.f};
        sc[f][s4] = mfma_bf16(ka[s4], qf[f], z);
      }
    __builtin_amdgcn_s_setprio(0);

    // P = exp2(sc) (sc >= 0; base cancels) -> in-register PV B operands
    u32x4 pf0[2], pf1[2];
#pragma unroll
    for (int f = 0; f < 2; f++) {
      pf0[f][0] = pk2(exp2f(sc[f][0][0]), exp2f(sc[f][0][1]));
      pf0[f][1] = pk2(exp2f(sc[f][0][2]), exp2f(sc[f][0][3]));
      pf0[f][2] = pk2(exp2f(sc[f][1][0]), exp2f(sc[f][1][1]));
      pf0[f][3] = pk2(exp2f(sc[f][1][2]), exp2f(sc[f][1][3]));
      pf1[f][0] = pk2(exp2f(sc[f][2][0]), exp2f(sc[f][2][1]));
      pf1[f][1] = pk2(exp2f(sc[f][2][2]), exp2f(sc[f][2][3]));
      pf1[f][2] = pk2(exp2f(sc[f][3][0]), exp2f(sc[f][3][1]));
      pf1[f][3] = pk2(exp2f(sc[f][3][2]), exp2f(sc[f][3][3]));
    }

    u32x4 va00 = *(const u32x4*)&vs[(lq << 6) + ((kg ^ vslot) << 3)];
    u32x4 va01 = *(const u32x4*)&vs[(lq << 6) + (((4 | kg) ^ vslot) << 3)];
    u32x4 va10 = *(const u32x4*)&vs[((16 + lq) << 6) + ((kg ^ vslot) << 3)];
    u32x4 va11 = *(const u32x4*)&vs[((16 + lq) << 6) + (((4 | kg) ^ vslot) << 3)];
#pragma unroll
    for (int f = 0; f < 2; f++) {
      __builtin_amdgcn_s_setprio(1);
      oLo[f] = mfma_bf16(va00, pf0[f], oLo[f]);
      oLo[f] = mfma_bf16(va01, pf1[f], oLo[f]);
      oHi[f] = mfma_bf16(va10, pf0[f], oHi[f]);
      oHi[f] = mfma_bf16(va11, pf1[f], oHi[f]);
      lac[f] = mfma_bf16(ones, pf0[f], lac[f]);
      lac[f] = mfma_bf16(ones, pf1[f], lac[f]);
      __builtin_amdgcn_s_setprio(0);
    }
    cb = (cb + 1 == 3) ? 0 : cb + 1;
  }

  // Partials out: fp32 unnormalized o + l (fixed base -> combine sums)
#pragma unroll
  for (int f = 0; f < 2; f++) {
    const int qrow = q0 + f * 16 + lq;
    const size_t sidx = ((size_t)p * 32 + bh) * SEQ + qrow;
    if (kg == 0) lP[sidx] = lac[f][0];
    float* op = oP + sidx * 32;
    *(f32x4*)(op + kg * 4) = oLo[f];
    *(f32x4*)(op + 16 + kg * 4) = oHi[f];
  }
}

// Merge 2 partial states: out = (o0+o1) / (l0+l1), write bf16
__global__ __launch_bounds__(256) void attn_combine_kernel(
    const float* __restrict__ oP, const float* __restrict__ lP,
    unsigned short* __restrict__ O) {
  const int t = blockIdx.x * blockDim.x + threadIdx.x;
  const int bh = t >> 11;
  const int qrow = t & 2047;
  const int b = bh >> 3, h = bh & 7;

  const size_t s0 = (size_t)bh * SEQ + qrow;
  const size_t s1 = ((size_t)32 + bh) * SEQ + qrow;
  const float inv = 1.f / (lP[s0] + lP[s1]);

  const float* o0 = oP + s0 * 32;
  const float* o1 = oP + s1 * 32;
  unsigned short* outp =
      O + (size_t)b * SEQ * DMODEL + (size_t)qrow * DMODEL + h * 32;
#pragma unroll
  for (int i = 0; i < 8; i++) {
    float4 a = *(const float4*)(o0 + i * 4);
    float4 c = *(const float4*)(o1 + i * 4);
    uint2 v;
    v.x = pk2((a.x + c.x) * inv, (a.y + c.y) * inv);
    v.y = pk2((a.z + c.z) * inv, (a.w + c.w) * inv);
    *(uint2*)(outp + i * 4) = v;
  }
}

// ---------------- LayerNorm of relu(P0+P1)+res (split-K combine) --------
__global__ __launch_bounds__(256) void ln_fuse_kernel(
    const float* __restrict__ P0, const float* __restrict__ P1,
    const float* __restrict__ res, const float* __restrict__ g,
    const float* __restrict__ b, float* __restrict__ Y,
    unsigned short* __restrict__ Yb) {
  const int wid = (blockIdx.x * blockDim.x + threadIdx.x) >> 6;
  const int lane = threadIdx.x & 63;
  const size_t off = (size_t)wid * DMODEL + lane * 4;
  float4 p0 = *(const float4*)(P0 + off);
  float4 p1 = *(const float4*)(P1 + off);
  float4 r = *(const float4*)(res + off);
  float4 v;
  v.x = fmaxf(p0.x + p1.x, 0.f) + r.x;
  v.y = fmaxf(p0.y + p1.y, 0.f) + r.y;
  v.z = fmaxf(p0.z + p1.z, 0.f) + r.z;
  v.w = fmaxf(p0.w + p1.w, 0.f) + r.w;
  float s = v.x + v.y + v.z + v.w;
  float s2 = v.x * v.x + v.y * v.y + v.z * v.z + v.w * v.w;
#pragma unroll
  for (int o = 32; o >= 1; o >>= 1) {
    s += __shfl_xor(s, o, 64);
    s2 += __shfl_xor(s2, o, 64);
  }
  const float mu = s * (1.f / DMODEL);
  const float var = s2 * (1.f / DMODEL) - mu * mu;
  const float inv = rsqrtf(var + LN_EPS);
  float4 gv = *(const float4*)(g + lane * 4);
  float4 bv = *(const float4*)(b + lane * 4);
  float4 o;
  o.x = (v.x - mu) * inv * gv.x + bv.x;
  o.y = (v.y - mu) * inv * gv.y + bv.y;
  o.z = (v.z - mu) * inv * gv.z + bv.z;
  o.w = (v.w - mu) * inv * gv.w + bv.w;
  if (Y) *(float4*)(Y + off) = o;
  if (Yb) {
    uint2 pk;
    pk.x = pk2(o.x, o.y);
    pk.y = pk2(o.z, o.w);
    *(uint2*)(Yb + off) = pk;
  }
}

extern "C" void kernel_launch(void* const* d_in, const int* in_sizes, int n_in,
                              void* d_out, int out_size, void* d_ws, size_t ws_size,
                              hipStream_t stream) {
  const float* x = (const float*)d_in[0];
  const float* g1 = (const float*)d_in[13];
  const float* b1 = (const float*)d_in[14];
  const float* g2 = (const float*)d_in[15];
  const float* b2 = (const float*)d_in[16];
  const float* g3 = (const float*)d_in[17];
  const float* b3 = (const float*)d_in[18];
  const float* g4 = (const float*)d_in[19];
  const float* b4 = (const float*)d_in[20];

  float* out = (float*)d_out;
  float* ws = (float*)d_ws;
  const size_t NM = (size_t)MROWS * DMODEL;
  const size_t ML = (size_t)32 * SEQ;  // 65536 rows per split
  const float QSCALE = 0.17677669529663687f * 1.4426950408889634f;

  float* F0 = ws;                       // vt alias only
  float* F1 = ws + NM;                  // fp32 residual stream
  // union [2NM,4NM): fb bf16 8192x1024 (FFN) | attn oP fp32 | o-proj P0/P1
  char* U = (char*)(ws + 2 * NM);
  unsigned short* fb = (unsigned short*)U;
  float* oP = (float*)U;
  float* oprojP0 = (float*)U;
  float* oprojP1 = (float*)U + NM;
  float* lP = ws + 4 * NM;  // 2 x 65536 fp32
  unsigned short* xb = (unsigned short*)(lP + 2 * ML);
  unsigned short* qb = xb + NM;
  unsigned short* kb = qb + NM;
  unsigned short* ob = kb + NM;
  unsigned short* nb = ob + NM;
  unsigned short* wb = nb + NM;
  unsigned short* qkv1 = wb;
  unsigned short* qkv2 = wb + 3 * 65536;
  unsigned short* o1w = wb + 6 * 65536;
  unsigned short* o2w = wb + 7 * 65536;
  unsigned short* f11 = wb + 8 * 65536;
  unsigned short* f21 = f11 + 262144;
  unsigned short* f12 = f21 + 262144;
  unsigned short* f22 = f12 + 262144;
  unsigned short* vt = (unsigned short*)F0;   // aliases F0
  float* f2P0 = (float*)qb;  // qb+kb span = NM floats (dead after attn)
  float* f2P1 = (float*)ob;  // ob+nb span = NM floats (dead after f1)

  {
    CvtArgs a;
    a.s[0] = x; a.d[0] = xb; a.n4[0] = (int)(NM / 4);
    unsigned short* wd[12] = {qkv1, qkv1 + 65536, qkv1 + 131072, o1w,
                              qkv2, qkv2 + 65536, qkv2 + 131072, o2w,
                              f11, f21, f12, f22};
    for (int i = 0; i < 12; i++) {
      a.s[i + 1] = (const float*)d_in[i + 1];
      a.d[i + 1] = wd[i];
      a.n4[i + 1] = (i < 8) ? 65536 / 4 : 262144 / 4;
    }
    cvt_kernel<<<dim3(256, 13), 256, 0, stream>>>(a);
  }

  auto gemm = [&](const unsigned short* A, const unsigned short* W,
                  unsigned short* oB, unsigned short* oB2,
                  unsigned short* oVT, float bs, int N, int K) {
    const int ntx = N / 64;
    gemm_bf16_kernel<<<ntx * (MROWS / 64), 256, 0, stream>>>(
        A, W, nullptr, nullptr, oB, oB2, oVT, nullptr, nullptr, bs, N, K,
        ntx, 0);
  };
  auto gemm_split = [&](const unsigned short* A, const unsigned short* W,
                        float* P0, float* P1, int N, int K) {
    const int ntx = N / 64;
    gemm_bf16_kernel<<<ntx * (MROWS / 64) * 2, 256, 0, stream>>>(
        A, W, nullptr, nullptr, nullptr, nullptr, nullptr, P0, P1, 1.f, N, K,
        ntx, 1);
  };
  auto attn = [&](const unsigned short* Q, const unsigned short* K,
                  const unsigned short* VT, unsigned short* O) {
    attn_mfma_kernel<<<dim3(SEQ / 128, 32, 2), 256, 0, stream>>>(
        Q, K, VT, oP, lP, SEQ / 2);
    attn_combine_kernel<<<65536 / 256, 256, 0, stream>>>(oP, lP, O);
  };
  auto ln_fuse = [&](const float* P0, const float* P1, const float* res,
                     const float* gm, const float* bt, float* Y,
                     unsigned short* Yb) {
    ln_fuse_kernel<<<MROWS / 4, 256, 0, stream>>>(P0, P1, res, gm, bt, Y, Yb);
  };

  // ---- Block 1 ----
  gemm(xb, qkv1, qb, kb, vt, QSCALE, 768, 256);        // fused QKV
  attn(qb, kb, vt, ob);                                // -> ob (bf16)
  gemm_split(ob, o1w, oprojP0, oprojP1, 256, 256);     // o-proj partials
  ln_fuse(oprojP0, oprojP1, x, g1, b1, F1, nb);        // x1n = LN(relu+x)
  gemm(nb, f11, fb, nullptr, nullptr, 1.f, 1024, 256); // f (bf16)
  gemm_split(fb, f21, f2P0, f2P1, 256, 1024);          // f2 partials
  ln_fuse(f2P0, f2P1, F1, g2, b2, F1, xb);             // block1 out

  // ---- Block 2 ----
  gemm(xb, qkv2, qb, kb, vt, QSCALE, 768, 256);
  attn(qb, kb, vt, ob);
  gemm_split(ob, o2w, oprojP0, oprojP1, 256, 256);
  ln_fuse(oprojP0, oprojP1, F1, g3, b3, F1, nb);
  gemm(nb, f12, fb, nullptr, nullptr, 1.f, 1024, 256);
  gemm_split(fb, f22, f2P0, f2P1, 256, 1024);
  ln_fuse(f2P0, f2P1, F1, g4, b4, out, nullptr);
}

// Round 15
// 235.787 us; speedup vs baseline: 1.0909x; 1.0473x over previous
//
#include <hip/hip_runtime.h>
#include <hip/hip_bf16.h>

// Encoder: B=4, S=2048, D=256, H=8, DK=32, DFF=1024, fp32 in/out.
// bf16 pipeline. Fixed-base softmax (scores>=0: ReLU'd q,k), l via
// ones-MFMA. Attn: K in LDS dbuf; V direct from L2 (2-deep reg prefetch);
// zero-dest QK MFMA. GEMM: 64x64/4-wave dbuf; N=256 GEMMs split-K=2
// with fused relu+add+LN combine.

#define MROWS 8192   // B*S
#define DMODEL 256
#define SEQ 2048
#define LN_EPS 1e-5f

typedef float f32x4 __attribute__((ext_vector_type(4)));
typedef unsigned int u32x4 __attribute__((ext_vector_type(4)));

__device__ __forceinline__ unsigned pk2(float lo, float hi) {
  union { __hip_bfloat162 h; unsigned u; } c;
  c.h = __float22bfloat162_rn(make_float2(lo, hi));
  return c.u;
}
__device__ __forceinline__ unsigned short bf1(float f) {
  union { __hip_bfloat16 h; unsigned short u; } c;
  c.h = __float2bfloat16(f);
  return c.u;
}

__device__ __forceinline__ f32x4 mfma_bf16(u32x4 a, u32x4 b, f32x4 c) {
  asm volatile("v_mfma_f32_16x16x32_bf16 %0, %1, %2, %0"
               : "+v"(c) : "v"(a), "v"(b));
  return c;
}
// zero-dest form: separate dest, shared read-only zero quad (no RMW copy)
__device__ __forceinline__ f32x4 mfma_bf16_z(u32x4 a, u32x4 b,
                                             const f32x4& z) {
  f32x4 d;
  asm volatile("v_mfma_f32_16x16x32_bf16 %0, %1, %2, %3"
               : "=v"(d) : "v"(a), "v"(b), "v"(z));
  return d;
}

__device__ __forceinline__ void gload_lds16(const void* g, void* l) {
  __builtin_amdgcn_global_load_lds(
      (const __attribute__((address_space(1))) void*)g,
      (__attribute__((address_space(3))) void*)l, 16, 0, 0);
}

// ---------------- fp32 -> bf16 batch convert ----------------
struct CvtArgs {
  const float* s[13];
  unsigned short* d[13];
  int n4[13];
};
__global__ __launch_bounds__(256) void cvt_kernel(CvtArgs a) {
  const int y = blockIdx.y;
  const int n4 = a.n4[y];
  const float4* src = (const float4*)a.s[y];
  unsigned short* dst = a.d[y];
  for (int i = blockIdx.x * 256 + threadIdx.x; i < n4; i += 256 * 256) {
    float4 v = src[i];
    uint2 o;
    o.x = pk2(v.x, v.y);
    o.y = pk2(v.z, v.w);
    *(uint2*)(dst + (size_t)i * 4) = o;
  }
}

// ---------------- bf16 MFMA GEMM: relu(A @ W^T) (+res) ----------------
// 256 threads, 4 waves (2x2), block 64x64, wave 32x32, BK=64, dbuf.
// splitk: grid doubled, lid&1 = K-slice, raw fp32 partial -> outP0/P1.
// Fused-QKV epilogue: n0<256 -> outB (bscale), [256,512) -> outB2,
// >=512 -> outVT (V^T [b*8+h][d][s]). XCD-swizzled 1D grid.
__global__ __launch_bounds__(256) void gemm_bf16_kernel(
    const unsigned short* __restrict__ A, const unsigned short* __restrict__ W,
    const float* __restrict__ res, float* __restrict__ outF,
    unsigned short* __restrict__ outB, unsigned short* __restrict__ outB2,
    unsigned short* __restrict__ outVT, float* __restrict__ outP0,
    float* __restrict__ outP1, float bscale, int N, int K, int ntx,
    int splitk) {
  __shared__ alignas(16) unsigned short As[2][64 * 64];
  __shared__ alignas(16) unsigned short Ws[2][64 * 64];
  const int tid = threadIdx.x;
  const int w = tid >> 6, lane = tid & 63;
  const int lq = lane & 15, kg = lane >> 4;
  const int wm = w >> 1, wn = w & 1;
  const int nwg = gridDim.x, cpx = nwg >> 3, bid = blockIdx.x;
  int lid = (bid & 7) * cpx + (bid >> 3);
  int kslice = 0;
  if (splitk) { kslice = lid & 1; lid >>= 1; }
  const int m0 = (lid / ntx) * 64, n0 = (lid % ntx) * 64;
  const int klen = splitk ? (K >> 1) : K;
  const unsigned short* Ab = A + (size_t)kslice * (K >> 1);
  const unsigned short* Wb = W + (size_t)kslice * (K >> 1);

  f32x4 acc[2][2] = {};

  auto STAGE = [&](int buf, int k0) {
#pragma unroll
    for (int i = 0; i < 2; i++) {
      const int li = i * 256 + tid;
      const int row = li >> 3, sl = (li & 7) ^ (row & 7);
      gload_lds16(Ab + (size_t)(m0 + row) * K + k0 + sl * 8,
                  (char*)As[buf] + (i * 256 + (tid & ~63)) * 16);
    }
#pragma unroll
    for (int i = 0; i < 2; i++) {
      const int li = i * 256 + tid;
      const int row = li >> 3, sl = (li & 7) ^ (row & 7);
      gload_lds16(Wb + (size_t)(n0 + row) * K + k0 + sl * 8,
                  (char*)Ws[buf] + (i * 256 + (tid & ~63)) * 16);
    }
  };

  const int nt = klen >> 6;
  STAGE(0, 0);
  for (int t = 0; t < nt; t++) {
    __syncthreads();  // drains vmcnt: buf[t&1] ready
    if (t + 1 < nt) STAGE((t + 1) & 1, (t + 1) << 6);
    const unsigned short* as = As[t & 1];
    const unsigned short* wsb = Ws[t & 1];
#pragma unroll
    for (int kk = 0; kk < 2; kk++) {
      const int sl = (((kk * 4 + kg) ^ (lq & 7)) << 3);
      u32x4 a0 = *(const u32x4*)&as[((wm * 32 + lq) << 6) + sl];
      u32x4 a1 = *(const u32x4*)&as[((wm * 32 + 16 + lq) << 6) + sl];
      u32x4 b0 = *(const u32x4*)&wsb[((wn * 32 + lq) << 6) + sl];
      u32x4 b1 = *(const u32x4*)&wsb[((wn * 32 + 16 + lq) << 6) + sl];
      __builtin_amdgcn_s_setprio(1);
      acc[0][0] = mfma_bf16(a0, b0, acc[0][0]);
      acc[0][1] = mfma_bf16(a0, b1, acc[0][1]);
      acc[1][0] = mfma_bf16(a1, b0, acc[1][0]);
      acc[1][1] = mfma_bf16(a1, b1, acc[1][1]);
      __builtin_amdgcn_s_setprio(0);
    }
  }

  // Epilogue: D row = kg*4+r, col = lq per 16x16 frag.
  if (splitk) {  // raw fp32 partial (no relu, no res)
    float* P = kslice ? outP1 : outP0;
#pragma unroll
    for (int mi = 0; mi < 2; mi++) {
      const int m = m0 + wm * 32 + mi * 16 + kg * 4;
#pragma unroll
      for (int nj = 0; nj < 2; nj++) {
        const int n = n0 + wn * 32 + nj * 16 + lq;
#pragma unroll
        for (int r = 0; r < 4; r++)
          P[(size_t)(m + r) * N + n] = acc[mi][nj][r];
      }
    }
  } else if (outVT && n0 >= 512) {  // V^T path (fused QKV)
#pragma unroll
    for (int mi = 0; mi < 2; mi++) {
      const int mb = m0 + wm * 32 + mi * 16 + kg * 4;
      const int bq = mb >> 11, s0 = mb & 2047;
#pragma unroll
      for (int nj = 0; nj < 2; nj++) {
        const int nn = n0 - 512 + wn * 32 + nj * 16 + lq;
        const int hh = nn >> 5, dd = nn & 31;
        uint2 pv;
        pv.x = pk2(fmaxf(acc[mi][nj][0], 0.f), fmaxf(acc[mi][nj][1], 0.f));
        pv.y = pk2(fmaxf(acc[mi][nj][2], 0.f), fmaxf(acc[mi][nj][3], 0.f));
        *(uint2*)(outVT + ((size_t)(bq * 8 + hh) * 32 + dd) * 2048 + s0) = pv;
      }
    }
  } else if (outB2 && n0 >= 256) {  // K path (fused QKV)
#pragma unroll
    for (int mi = 0; mi < 2; mi++) {
      const int m = m0 + wm * 32 + mi * 16 + kg * 4;
#pragma unroll
      for (int nj = 0; nj < 2; nj++) {
        const int nn = n0 - 256 + wn * 32 + nj * 16 + lq;
#pragma unroll
        for (int r = 0; r < 4; r++)
          outB2[(size_t)(m + r) * 256 + nn] = bf1(fmaxf(acc[mi][nj][r], 0.f));
      }
    }
  } else {
    const int ldo = (outB2 || outVT) ? 256 : N;  // fused-Q path uses 256
#pragma unroll
    for (int mi = 0; mi < 2; mi++) {
      const int m = m0 + wm * 32 + mi * 16 + kg * 4;
#pragma unroll
      for (int nj = 0; nj < 2; nj++) {
        const int n = n0 + wn * 32 + nj * 16 + lq;
#pragma unroll
        for (int r = 0; r < 4; r++) {
          float v = fmaxf(acc[mi][nj][r], 0.f);
          if (res) v += res[(size_t)(m + r) * N + n];
          if (outF) outF[(size_t)(m + r) * N + n] = v;
          if (outB) outB[(size_t)(m + r) * ldo + n] = bf1(v * bscale);
        }
      }
    }
  }
}

// ---------------- MFMA flash attention, fixed-base softmax ----------------
// 4 waves x 32 q rows (2 q-frags), 64 keys/step. K tile in LDS dbuf
// (gload_lds, swizzled source); V^T read DIRECTLY from global (L2-hot),
// 2-deep named-register prefetch. Zero-dest QK MFMA (no acc zero-movs).
// Permuted-K QK^T (P feeds PV in-register), KV-split2, fp32 partials.
__global__ __launch_bounds__(256) void attn_mfma_kernel(
    const unsigned short* __restrict__ Q, const unsigned short* __restrict__ K,
    const unsigned short* __restrict__ VT, float* __restrict__ oP,
    float* __restrict__ lP, int nkeys) {
  __shared__ alignas(16) unsigned short Ks[2][64 * 32];  // 8 KB dbuf

  const int tid = threadIdx.x;
  const int w = tid >> 6;
  const int lane = tid & 63;
  const int lq = lane & 15;
  const int kg = lane >> 4;
  const int bh = blockIdx.y, b = bh >> 3, h = bh & 7;
  const int p = blockIdx.z;
  const int q0 = blockIdx.x * 128 + w * 32;
  const size_t base = (size_t)b * SEQ * DMODEL + h * 32;

  u32x4 qf[2];
  qf[0] = *(const u32x4*)(Q + base + (size_t)(q0 + lq) * DMODEL + kg * 8);
  qf[1] = *(const u32x4*)(Q + base + (size_t)(q0 + 16 + lq) * DMODEL + kg * 8);

  f32x4 oLo[2] = {{0.f, 0.f, 0.f, 0.f}, {0.f, 0.f, 0.f, 0.f}};
  f32x4 oHi[2] = {{0.f, 0.f, 0.f, 0.f}, {0.f, 0.f, 0.f, 0.f}};
  f32x4 lac[2] = {{0.f, 0.f, 0.f, 0.f}, {0.f, 0.f, 0.f, 0.f}};
  const f32x4 zq = {0.f, 0.f, 0.f, 0.f};  // shared zero C operand
  const unsigned ONE2 = 0x3F803F80u;
  const u32x4 ones = {ONE2, ONE2, ONE2, ONE2};

  const int kg4 = (lane & 3) ^ ((lane >> 3) & 3);  // K src slot swizzle
  const unsigned short* vtb = VT + (size_t)bh * 32 * 2048;

  // Permuted ka rows (R11): PV B-operand assembles in-register.
  int krow[4], kslt[4];
#pragma unroll
  for (int s4 = 0; s4 < 4; s4++) {
    const int g = (s4 >> 1) * 32 + ((lq >> 2) << 3) + ((s4 & 1) << 2) + (lq & 3);
    krow[s4] = g;
    kslt[s4] = kg ^ ((g >> 1) & 3);
  }

  // V^T per-lane base pointers (16B contiguous per load, L2-resident).
  const unsigned short* vp0 = vtb + (size_t)lq * 2048 + kg * 8;
  const unsigned short* vp1 = vtb + (size_t)(16 + lq) * 2048 + kg * 8;

  auto STAGE = [&](int buf, int kt) {
    const int kr = w * 16 + (lane >> 2);
    gload_lds16(K + base + (size_t)(kt + kr) * DMODEL + kg4 * 8,
                (char*)Ks[buf] + w * 1024);
  };
  auto LOADV = [&](u32x4 (&va)[4], int kt) {
    va[0] = *(const u32x4*)(vp0 + kt);
    va[1] = *(const u32x4*)(vp0 + kt + 32);
    va[2] = *(const u32x4*)(vp1 + kt);
    va[3] = *(const u32x4*)(vp1 + kt + 32);
  };

  auto COMPUTE = [&](const unsigned short* ks, const u32x4 (&va)[4]) {
    u32x4 ka[4];
#pragma unroll
    for (int s4 = 0; s4 < 4; s4++)
      ka[s4] = *(const u32x4*)&ks[(krow[s4] << 5) + (kslt[s4] << 3)];

    f32x4 sc[2][4];
    __builtin_amdgcn_s_setprio(1);
#pragma unroll
    for (int f = 0; f < 2; f++)
#pragma unroll
      for (int s4 = 0; s4 < 4; s4++)
        sc[f][s4] = mfma_bf16_z(ka[s4], qf[f], zq);
    __builtin_amdgcn_s_setprio(0);

    // P = exp2(sc) (sc >= 0; base cancels) -> in-register PV B operands
    u32x4 pf0[2], pf1[2];
#pragma unroll
    for (int f = 0; f < 2; f++) {
      pf0[f][0] = pk2(exp2f(sc[f][0][0]), exp2f(sc[f][0][1]));
      pf0[f][1] = pk2(exp2f(sc[f][0][2]), exp2f(sc[f][0][3]));
      pf0[f][2] = pk2(exp2f(sc[f][1][0]), exp2f(sc[f][1][1]));
      pf0[f][3] = pk2(exp2f(sc[f][1][2]), exp2f(sc[f][1][3]));
      pf1[f][0] = pk2(exp2f(sc[f][2][0]), exp2f(sc[f][2][1]));
      pf1[f][1] = pk2(exp2f(sc[f][2][2]), exp2f(sc[f][2][3]));
      pf1[f][2] = pk2(exp2f(sc[f][3][0]), exp2f(sc[f][3][1]));
      pf1[f][3] = pk2(exp2f(sc[f][3][2]), exp2f(sc[f][3][3]));
    }

#pragma unroll
    for (int f = 0; f < 2; f++) {
      __builtin_amdgcn_s_setprio(1);
      oLo[f] = mfma_bf16(va[0], pf0[f], oLo[f]);
      oLo[f] = mfma_bf16(va[1], pf1[f], oLo[f]);
      oHi[f] = mfma_bf16(va[2], pf0[f], oHi[f]);
      oHi[f] = mfma_bf16(va[3], pf1[f], oHi[f]);
      lac[f] = mfma_bf16(ones, pf0[f], lac[f]);
      lac[f] = mfma_bf16(ones, pf1[f], lac[f]);
      __builtin_amdgcn_s_setprio(0);
    }
  };

  const int kbeg = p * nkeys;
  const int nt = nkeys >> 6;  // 16 (even)
  u32x4 vaA[4], vaB[4];
  STAGE(0, kbeg);
  LOADV(vaA, kbeg);
  for (int t = 0; t < nt; t += 2) {
    __syncthreads();  // K buf0 (tile t) ready
    if (t + 1 < nt) { STAGE(1, kbeg + (t + 1) * 64); LOADV(vaB, (t + 1) * 64); }
    COMPUTE(&Ks[0][0], vaA);
    __syncthreads();  // all waves done reading buf0; buf1 (t+1) ready next
    if (t + 2 < nt) { STAGE(0, kbeg + (t + 2) * 64); LOADV(vaA, (t + 2) * 64); }
    if (t + 1 < nt) COMPUTE(&Ks[1][0], vaB);
  }

  // Partials out: fp32 unnormalized o + l (fixed base -> combine sums)
#pragma unroll
  for (int f = 0; f < 2; f++) {
    const int qrow = q0 + f * 16 + lq;
    const size_t sidx = ((size_t)p * 32 + bh) * SEQ + qrow;
    if (kg == 0) lP[sidx] = lac[f][0];
    float* op = oP + sidx * 32;
    *(f32x4*)(op + kg * 4) = oLo[f];
    *(f32x4*)(op + 16 + kg * 4) = oHi[f];
  }
}

// Merge 2 partial states: out = (o0+o1) / (l0+l1), write bf16
__global__ __launch_bounds__(256) void attn_combine_kernel(
    const float* __restrict__ oP, const float* __restrict__ lP,
    unsigned short* __restrict__ O) {
  const int t = blockIdx.x * blockDim.x + threadIdx.x;
  const int bh = t >> 11;
  const int qrow = t & 2047;
  const int b = bh >> 3, h = bh & 7;

  const size_t s0 = (size_t)bh * SEQ + qrow;
  const size_t s1 = ((size_t)32 + bh) * SEQ + qrow;
  const float inv = 1.f / (lP[s0] + lP[s1]);

  const float* o0 = oP + s0 * 32;
  const float* o1 = oP + s1 * 32;
  unsigned short* outp =
      O + (size_t)b * SEQ * DMODEL + (size_t)qrow * DMODEL + h * 32;
#pragma unroll
  for (int i = 0; i < 8; i++) {
    float4 a = *(const float4*)(o0 + i * 4);
    float4 c = *(const float4*)(o1 + i * 4);
    uint2 v;
    v.x = pk2((a.x + c.x) * inv, (a.y + c.y) * inv);
    v.y = pk2((a.z + c.z) * inv, (a.w + c.w) * inv);
    *(uint2*)(outp + i * 4) = v;
  }
}

// ---------------- LayerNorm of relu(P0+P1)+res (split-K combine) --------
__global__ __launch_bounds__(256) void ln_fuse_kernel(
    const float* __restrict__ P0, const float* __restrict__ P1,
    const float* __restrict__ res, const float* __restrict__ g,
    const float* __restrict__ b, float* __restrict__ Y,
    unsigned short* __restrict__ Yb) {
  const int wid = (blockIdx.x * blockDim.x + threadIdx.x) >> 6;
  const int lane = threadIdx.x & 63;
  const size_t off = (size_t)wid * DMODEL + lane * 4;
  float4 p0 = *(const float4*)(P0 + off);
  float4 p1 = *(const float4*)(P1 + off);
  float4 r = *(const float4*)(res + off);
  float4 v;
  v.x = fmaxf(p0.x + p1.x, 0.f) + r.x;
  v.y = fmaxf(p0.y + p1.y, 0.f) + r.y;
  v.z = fmaxf(p0.z + p1.z, 0.f) + r.z;
  v.w = fmaxf(p0.w + p1.w, 0.f) + r.w;
  float s = v.x + v.y + v.z + v.w;
  float s2 = v.x * v.x + v.y * v.y + v.z * v.z + v.w * v.w;
#pragma unroll
  for (int o = 32; o >= 1; o >>= 1) {
    s += __shfl_xor(s, o, 64);
    s2 += __shfl_xor(s2, o, 64);
  }
  const float mu = s * (1.f / DMODEL);
  const float var = s2 * (1.f / DMODEL) - mu * mu;
  const float inv = rsqrtf(var + LN_EPS);
  float4 gv = *(const float4*)(g + lane * 4);
  float4 bv = *(const float4*)(b + lane * 4);
  float4 o;
  o.x = (v.x - mu) * inv * gv.x + bv.x;
  o.y = (v.y - mu) * inv * gv.y + bv.y;
  o.z = (v.z - mu) * inv * gv.z + bv.z;
  o.w = (v.w - mu) * inv * gv.w + bv.w;
  if (Y) *(float4*)(Y + off) = o;
  if (Yb) {
    uint2 pk;
    pk.x = pk2(o.x, o.y);
    pk.y = pk2(o.z, o.w);
    *(uint2*)(Yb + off) = pk;
  }
}

extern "C" void kernel_launch(void* const* d_in, const int* in_sizes, int n_in,
                              void* d_out, int out_size, void* d_ws, size_t ws_size,
                              hipStream_t stream) {
  const float* x = (const float*)d_in[0];
  const float* g1 = (const float*)d_in[13];
  const float* b1 = (const float*)d_in[14];
  const float* g2 = (const float*)d_in[15];
  const float* b2 = (const float*)d_in[16];
  const float* g3 = (const float*)d_in[17];
  const float* b3 = (const float*)d_in[18];
  const float* g4 = (const float*)d_in[19];
  const float* b4 = (const float*)d_in[20];

  float* out = (float*)d_out;
  float* ws = (float*)d_ws;
  const size_t NM = (size_t)MROWS * DMODEL;
  const size_t ML = (size_t)32 * SEQ;  // 65536 rows per split
  const float QSCALE = 0.17677669529663687f * 1.4426950408889634f;

  float* F0 = ws;                       // vt alias only
  float* F1 = ws + NM;                  // fp32 residual stream
  // union [2NM,4NM): fb bf16 8192x1024 (FFN) | attn oP fp32 | o-proj P0/P1
  char* U = (char*)(ws + 2 * NM);
  unsigned short* fb = (unsigned short*)U;
  float* oP = (float*)U;
  float* oprojP0 = (float*)U;
  float* oprojP1 = (float*)U + NM;
  float* lP = ws + 4 * NM;  // 2 x 65536 fp32
  unsigned short* xb = (unsigned short*)(lP + 2 * ML);
  unsigned short* qb = xb + NM;
  unsigned short* kb = qb + NM;
  unsigned short* ob = kb + NM;
  unsigned short* nb = ob + NM;
  unsigned short* wb = nb + NM;
  unsigned short* qkv1 = wb;
  unsigned short* qkv2 = wb + 3 * 65536;
  unsigned short* o1w = wb + 6 * 65536;
  unsigned short* o2w = wb + 7 * 65536;
  unsigned short* f11 = wb + 8 * 65536;
  unsigned short* f21 = f11 + 262144;
  unsigned short* f12 = f21 + 262144;
  unsigned short* f22 = f12 + 262144;
  unsigned short* vt = (unsigned short*)F0;   // aliases F0
  float* f2P0 = (float*)qb;  // qb+kb span = NM floats (dead after attn)
  float* f2P1 = (float*)ob;  // ob+nb span = NM floats (dead after f1)

  {
    CvtArgs a;
    a.s[0] = x; a.d[0] = xb; a.n4[0] = (int)(NM / 4);
    unsigned short* wd[12] = {qkv1, qkv1 + 65536, qkv1 + 131072, o1w,
                              qkv2, qkv2 + 65536, qkv2 + 131072, o2w,
                              f11, f21, f12, f22};
    for (int i = 0; i < 12; i++) {
      a.s[i + 1] = (const float*)d_in[i + 1];
      a.d[i + 1] = wd[i];
      a.n4[i + 1] = (i < 8) ? 65536 / 4 : 262144 / 4;
    }
    cvt_kernel<<<dim3(256, 13), 256, 0, stream>>>(a);
  }

  auto gemm = [&](const unsigned short* A, const unsigned short* W,
                  unsigned short* oB, unsigned short* oB2,
                  unsigned short* oVT, float bs, int N, int K) {
    const int ntx = N / 64;
    gemm_bf16_kernel<<<ntx * (MROWS / 64), 256, 0, stream>>>(
        A, W, nullptr, nullptr, oB, oB2, oVT, nullptr, nullptr, bs, N, K,
        ntx, 0);
  };
  auto gemm_split = [&](const unsigned short* A, const unsigned short* W,
                        float* P0, float* P1, int N, int K) {
    const int ntx = N / 64;
    gemm_bf16_kernel<<<ntx * (MROWS / 64) * 2, 256, 0, stream>>>(
        A, W, nullptr, nullptr, nullptr, nullptr, nullptr, P0, P1, 1.f, N, K,
        ntx, 1);
  };
  auto attn = [&](const unsigned short* Q, const unsigned short* K,
                  const unsigned short* VT, unsigned short* O) {
    attn_mfma_kernel<<<dim3(SEQ / 128, 32, 2), 256, 0, stream>>>(
        Q, K, VT, oP, lP, SEQ / 2);
    attn_combine_kernel<<<65536 / 256, 256, 0, stream>>>(oP, lP, O);
  };
  auto ln_fuse = [&](const float* P0, const float* P1, const float* res,
                     const float* gm, const float* bt, float* Y,
                     unsigned short* Yb) {
    ln_fuse_kernel<<<MROWS / 4, 256, 0, stream>>>(P0, P1, res, gm, bt, Y, Yb);
  };

  // ---- Block 1 ----
  gemm(xb, qkv1, qb, kb, vt, QSCALE, 768, 256);        // fused QKV
  attn(qb, kb, vt, ob);                                // -> ob (bf16)
  gemm_split(ob, o1w, oprojP0, oprojP1, 256, 256);     // o-proj partials
  ln_fuse(oprojP0, oprojP1, x, g1, b1, F1, nb);        // x1n = LN(relu+x)
  gemm(nb, f11, fb, nullptr, nullptr, 1.f, 1024, 256); // f (bf16)
  gemm_split(fb, f21, f2P0, f2P1, 256, 1024);          // f2 partials
  ln_fuse(f2P0, f2P1, F1, g2, b2, F1, xb);             // block1 out

  // ---- Block 2 ----
  gemm(xb, qkv2, qb, kb, vt, QSCALE, 768, 256);
  attn(qb, kb, vt, ob);
  gemm_split(ob, o2w, oprojP0, oprojP1, 256, 256);
  ln_fuse(oprojP0, oprojP1, F1, g3, b3, F1, nb);
  gemm(nb, f12, fb, nullptr, nullptr, 1.f, 1024, 256);
  gemm_split(fb, f22, f2P0, f2P1, 256, 1024);
  ln_fuse(f2P0, f2P1, F1, g4, b4, out, nullptr);
}

// Round 16
// 219.054 us; speedup vs baseline: 1.1742x; 1.0764x over previous
//
#include <hip/hip_runtime.h>
#include <hip/hip_bf16.h>

// Encoder: B=4, S=2048, D=256, H=8, DK=32, DFF=1024, fp32 in/out.
// bf16 pipeline. Fixed-base softmax (scores>=0: ReLU'd q,k), l via
// ones-MFMA. Attn: K in LDS dbuf; V direct from L2 (reg prefetch);
// zero-dest QK MFMA; NATIVE v_exp_f32 (not OCML exp2f). GEMM:
// 64x64/4-wave dbuf; N=256 GEMMs split-K=2 + fused relu+add+LN combine.

#define MROWS 8192   // B*S
#define DMODEL 256
#define SEQ 2048
#define LN_EPS 1e-5f

typedef float f32x4 __attribute__((ext_vector_type(4)));
typedef unsigned int u32x4 __attribute__((ext_vector_type(4)));

__device__ __forceinline__ unsigned pk2(float lo, float hi) {
  union { __hip_bfloat162 h; unsigned u; } c;
  c.h = __float22bfloat162_rn(make_float2(lo, hi));
  return c.u;
}
__device__ __forceinline__ unsigned short bf1(float f) {
  union { __hip_bfloat16 h; unsigned short u; } c;
  c.h = __float2bfloat16(f);
  return c.u;
}
// native 2^x: single v_exp_f32 (exp2f w/o -ffast-math is the multi-inst
// OCML precise path -- ~15 VALU insts each, the R14 VALU hog)
__device__ __forceinline__ float fexp2(float x) {
  return __builtin_amdgcn_exp2f(x);
}

__device__ __forceinline__ f32x4 mfma_bf16(u32x4 a, u32x4 b, f32x4 c) {
  asm volatile("v_mfma_f32_16x16x32_bf16 %0, %1, %2, %0"
               : "+v"(c) : "v"(a), "v"(b));
  return c;
}
// zero-dest form: separate dest, shared read-only zero quad (no RMW copy)
__device__ __forceinline__ f32x4 mfma_bf16_z(u32x4 a, u32x4 b,
                                             const f32x4& z) {
  f32x4 d;
  asm volatile("v_mfma_f32_16x16x32_bf16 %0, %1, %2, %3"
               : "=v"(d) : "v"(a), "v"(b), "v"(z));
  return d;
}

__device__ __forceinline__ void gload_lds16(const void* g, void* l) {
  __builtin_amdgcn_global_load_lds(
      (const __attribute__((address_space(1))) void*)g,
      (__attribute__((address_space(3))) void*)l, 16, 0, 0);
}

// ---------------- fp32 -> bf16 batch convert ----------------
struct CvtArgs {
  const float* s[13];
  unsigned short* d[13];
  int n4[13];
};
__global__ __launch_bounds__(256) void cvt_kernel(CvtArgs a) {
  const int y = blockIdx.y;
  const int n4 = a.n4[y];
  const float4* src = (const float4*)a.s[y];
  unsigned short* dst = a.d[y];
  for (int i = blockIdx.x * 256 + threadIdx.x; i < n4; i += 256 * 256) {
    float4 v = src[i];
    uint2 o;
    o.x = pk2(v.x, v.y);
    o.y = pk2(v.z, v.w);
    *(uint2*)(dst + (size_t)i * 4) = o;
  }
}

// ---------------- bf16 MFMA GEMM: relu(A @ W^T) (+res) ----------------
// 256 threads, 4 waves (2x2), block 64x64, wave 32x32, BK=64, dbuf.
// splitk: grid doubled, lid&1 = K-slice, raw fp32 partial -> outP0/P1.
// Fused-QKV epilogue: n0<256 -> outB (bscale), [256,512) -> outB2,
// >=512 -> outVT (V^T [b*8+h][d][s]). XCD-swizzled 1D grid.
__global__ __launch_bounds__(256) void gemm_bf16_kernel(
    const unsigned short* __restrict__ A, const unsigned short* __restrict__ W,
    const float* __restrict__ res, float* __restrict__ outF,
    unsigned short* __restrict__ outB, unsigned short* __restrict__ outB2,
    unsigned short* __restrict__ outVT, float* __restrict__ outP0,
    float* __restrict__ outP1, float bscale, int N, int K, int ntx,
    int splitk) {
  __shared__ alignas(16) unsigned short As[2][64 * 64];
  __shared__ alignas(16) unsigned short Ws[2][64 * 64];
  const int tid = threadIdx.x;
  const int w = tid >> 6, lane = tid & 63;
  const int lq = lane & 15, kg = lane >> 4;
  const int wm = w >> 1, wn = w & 1;
  const int nwg = gridDim.x, cpx = nwg >> 3, bid = blockIdx.x;
  int lid = (bid & 7) * cpx + (bid >> 3);
  int kslice = 0;
  if (splitk) { kslice = lid & 1; lid >>= 1; }
  const int m0 = (lid / ntx) * 64, n0 = (lid % ntx) * 64;
  const int klen = splitk ? (K >> 1) : K;
  const unsigned short* Ab = A + (size_t)kslice * (K >> 1);
  const unsigned short* Wb = W + (size_t)kslice * (K >> 1);

  f32x4 acc[2][2] = {};

  auto STAGE = [&](int buf, int k0) {
#pragma unroll
    for (int i = 0; i < 2; i++) {
      const int li = i * 256 + tid;
      const int row = li >> 3, sl = (li & 7) ^ (row & 7);
      gload_lds16(Ab + (size_t)(m0 + row) * K + k0 + sl * 8,
                  (char*)As[buf] + (i * 256 + (tid & ~63)) * 16);
    }
#pragma unroll
    for (int i = 0; i < 2; i++) {
      const int li = i * 256 + tid;
      const int row = li >> 3, sl = (li & 7) ^ (row & 7);
      gload_lds16(Wb + (size_t)(n0 + row) * K + k0 + sl * 8,
                  (char*)Ws[buf] + (i * 256 + (tid & ~63)) * 16);
    }
  };

  const int nt = klen >> 6;
  STAGE(0, 0);
  for (int t = 0; t < nt; t++) {
    __syncthreads();  // drains vmcnt: buf[t&1] ready
    if (t + 1 < nt) STAGE((t + 1) & 1, (t + 1) << 6);
    const unsigned short* as = As[t & 1];
    const unsigned short* wsb = Ws[t & 1];
#pragma unroll
    for (int kk = 0; kk < 2; kk++) {
      const int sl = (((kk * 4 + kg) ^ (lq & 7)) << 3);
      u32x4 a0 = *(const u32x4*)&as[((wm * 32 + lq) << 6) + sl];
      u32x4 a1 = *(const u32x4*)&as[((wm * 32 + 16 + lq) << 6) + sl];
      u32x4 b0 = *(const u32x4*)&wsb[((wn * 32 + lq) << 6) + sl];
      u32x4 b1 = *(const u32x4*)&wsb[((wn * 32 + 16 + lq) << 6) + sl];
      __builtin_amdgcn_s_setprio(1);
      acc[0][0] = mfma_bf16(a0, b0, acc[0][0]);
      acc[0][1] = mfma_bf16(a0, b1, acc[0][1]);
      acc[1][0] = mfma_bf16(a1, b0, acc[1][0]);
      acc[1][1] = mfma_bf16(a1, b1, acc[1][1]);
      __builtin_amdgcn_s_setprio(0);
    }
  }

  // Epilogue: D row = kg*4+r, col = lq per 16x16 frag.
  if (splitk) {  // raw fp32 partial (no relu, no res)
    float* P = kslice ? outP1 : outP0;
#pragma unroll
    for (int mi = 0; mi < 2; mi++) {
      const int m = m0 + wm * 32 + mi * 16 + kg * 4;
#pragma unroll
      for (int nj = 0; nj < 2; nj++) {
        const int n = n0 + wn * 32 + nj * 16 + lq;
#pragma unroll
        for (int r = 0; r < 4; r++)
          P[(size_t)(m + r) * N + n] = acc[mi][nj][r];
      }
    }
  } else if (outVT && n0 >= 512) {  // V^T path (fused QKV)
#pragma unroll
    for (int mi = 0; mi < 2; mi++) {
      const int mb = m0 + wm * 32 + mi * 16 + kg * 4;
      const int bq = mb >> 11, s0 = mb & 2047;
#pragma unroll
      for (int nj = 0; nj < 2; nj++) {
        const int nn = n0 - 512 + wn * 32 + nj * 16 + lq;
        const int hh = nn >> 5, dd = nn & 31;
        uint2 pv;
        pv.x = pk2(fmaxf(acc[mi][nj][0], 0.f), fmaxf(acc[mi][nj][1], 0.f));
        pv.y = pk2(fmaxf(acc[mi][nj][2], 0.f), fmaxf(acc[mi][nj][3], 0.f));
        *(uint2*)(outVT + ((size_t)(bq * 8 + hh) * 32 + dd) * 2048 + s0) = pv;
      }
    }
  } else if (outB2 && n0 >= 256) {  // K path (fused QKV)
#pragma unroll
    for (int mi = 0; mi < 2; mi++) {
      const int m = m0 + wm * 32 + mi * 16 + kg * 4;
#pragma unroll
      for (int nj = 0; nj < 2; nj++) {
        const int nn = n0 - 256 + wn * 32 + nj * 16 + lq;
#pragma unroll
        for (int r = 0; r < 4; r++)
          outB2[(size_t)(m + r) * 256 + nn] = bf1(fmaxf(acc[mi][nj][r], 0.f));
      }
    }
  } else {
    const int ldo = (outB2 || outVT) ? 256 : N;  // fused-Q path uses 256
#pragma unroll
    for (int mi = 0; mi < 2; mi++) {
      const int m = m0 + wm * 32 + mi * 16 + kg * 4;
#pragma unroll
      for (int nj = 0; nj < 2; nj++) {
        const int n = n0 + wn * 32 + nj * 16 + lq;
#pragma unroll
        for (int r = 0; r < 4; r++) {
          float v = fmaxf(acc[mi][nj][r], 0.f);
          if (res) v += res[(size_t)(m + r) * N + n];
          if (outF) outF[(size_t)(m + r) * N + n] = v;
          if (outB) outB[(size_t)(m + r) * ldo + n] = bf1(v * bscale);
        }
      }
    }
  }
}

// ---------------- MFMA flash attention, fixed-base softmax ----------------
// 4 waves x 32 q rows (2 q-frags), 64 keys/step. K tile in LDS dbuf
// (gload_lds, swizzled source); V^T read DIRECTLY from global (L2-hot),
// 2-deep named-register prefetch. Zero-dest QK MFMA; native v_exp_f32.
// Permuted-K QK^T (P feeds PV in-register), KV-split2, fp32 partials.
__global__ __launch_bounds__(256) void attn_mfma_kernel(
    const unsigned short* __restrict__ Q, const unsigned short* __restrict__ K,
    const unsigned short* __restrict__ VT, float* __restrict__ oP,
    float* __restrict__ lP, int nkeys) {
  __shared__ alignas(16) unsigned short Ks[2][64 * 32];  // 8 KB dbuf

  const int tid = threadIdx.x;
  const int w = tid >> 6;
  const int lane = tid & 63;
  const int lq = lane & 15;
  const int kg = lane >> 4;
  const int bh = blockIdx.y, b = bh >> 3, h = bh & 7;
  const int p = blockIdx.z;
  const int q0 = blockIdx.x * 128 + w * 32;
  const size_t base = (size_t)b * SEQ * DMODEL + h * 32;

  u32x4 qf[2];
  qf[0] = *(const u32x4*)(Q + base + (size_t)(q0 + lq) * DMODEL + kg * 8);
  qf[1] = *(const u32x4*)(Q + base + (size_t)(q0 + 16 + lq) * DMODEL + kg * 8);

  f32x4 oLo[2] = {{0.f, 0.f, 0.f, 0.f}, {0.f, 0.f, 0.f, 0.f}};
  f32x4 oHi[2] = {{0.f, 0.f, 0.f, 0.f}, {0.f, 0.f, 0.f, 0.f}};
  f32x4 lac[2] = {{0.f, 0.f, 0.f, 0.f}, {0.f, 0.f, 0.f, 0.f}};
  const f32x4 zq = {0.f, 0.f, 0.f, 0.f};  // shared zero C operand
  const unsigned ONE2 = 0x3F803F80u;
  const u32x4 ones = {ONE2, ONE2, ONE2, ONE2};

  const int kg4 = (lane & 3) ^ ((lane >> 3) & 3);  // K src slot swizzle
  const unsigned short* vtb = VT + (size_t)bh * 32 * 2048;

  // Permuted ka rows (R11): PV B-operand assembles in-register.
  int krow[4], kslt[4];
#pragma unroll
  for (int s4 = 0; s4 < 4; s4++) {
    const int g = (s4 >> 1) * 32 + ((lq >> 2) << 3) + ((s4 & 1) << 2) + (lq & 3);
    krow[s4] = g;
    kslt[s4] = kg ^ ((g >> 1) & 3);
  }

  // V^T per-lane base pointers (16B contiguous per load, L2-resident).
  const unsigned short* vp0 = vtb + (size_t)lq * 2048 + kg * 8;
  const unsigned short* vp1 = vtb + (size_t)(16 + lq) * 2048 + kg * 8;

  auto STAGE = [&](int buf, int kt) {
    const int kr = w * 16 + (lane >> 2);
    gload_lds16(K + base + (size_t)(kt + kr) * DMODEL + kg4 * 8,
                (char*)Ks[buf] + w * 1024);
  };
  auto LOADV = [&](u32x4 (&va)[4], int kt) {
    va[0] = *(const u32x4*)(vp0 + kt);
    va[1] = *(const u32x4*)(vp0 + kt + 32);
    va[2] = *(const u32x4*)(vp1 + kt);
    va[3] = *(const u32x4*)(vp1 + kt + 32);
  };

  auto COMPUTE = [&](const unsigned short* ks, const u32x4 (&va)[4]) {
    u32x4 ka[4];
#pragma unroll
    for (int s4 = 0; s4 < 4; s4++)
      ka[s4] = *(const u32x4*)&ks[(krow[s4] << 5) + (kslt[s4] << 3)];

    f32x4 sc[2][4];
    __builtin_amdgcn_s_setprio(1);
#pragma unroll
    for (int f = 0; f < 2; f++)
#pragma unroll
      for (int s4 = 0; s4 < 4; s4++)
        sc[f][s4] = mfma_bf16_z(ka[s4], qf[f], zq);
    __builtin_amdgcn_s_setprio(0);

    // P = 2^sc via native v_exp_f32 (sc >= 0; base cancels in o/l)
    u32x4 pf0[2], pf1[2];
#pragma unroll
    for (int f = 0; f < 2; f++) {
      pf0[f][0] = pk2(fexp2(sc[f][0][0]), fexp2(sc[f][0][1]));
      pf0[f][1] = pk2(fexp2(sc[f][0][2]), fexp2(sc[f][0][3]));
      pf0[f][2] = pk2(fexp2(sc[f][1][0]), fexp2(sc[f][1][1]));
      pf0[f][3] = pk2(fexp2(sc[f][1][2]), fexp2(sc[f][1][3]));
      pf1[f][0] = pk2(fexp2(sc[f][2][0]), fexp2(sc[f][2][1]));
      pf1[f][1] = pk2(fexp2(sc[f][2][2]), fexp2(sc[f][2][3]));
      pf1[f][2] = pk2(fexp2(sc[f][3][0]), fexp2(sc[f][3][1]));
      pf1[f][3] = pk2(fexp2(sc[f][3][2]), fexp2(sc[f][3][3]));
    }

#pragma unroll
    for (int f = 0; f < 2; f++) {
      __builtin_amdgcn_s_setprio(1);
      oLo[f] = mfma_bf16(va[0], pf0[f], oLo[f]);
      oLo[f] = mfma_bf16(va[1], pf1[f], oLo[f]);
      oHi[f] = mfma_bf16(va[2], pf0[f], oHi[f]);
      oHi[f] = mfma_bf16(va[3], pf1[f], oHi[f]);
      lac[f] = mfma_bf16(ones, pf0[f], lac[f]);
      lac[f] = mfma_bf16(ones, pf1[f], lac[f]);
      __builtin_amdgcn_s_setprio(0);
    }
  };

  const int kbeg = p * nkeys;
  const int nt = nkeys >> 6;  // 16 (even)
  u32x4 vaA[4], vaB[4];
  STAGE(0, kbeg);
  LOADV(vaA, kbeg);
  for (int t = 0; t < nt; t += 2) {
    __syncthreads();  // K buf0 (tile t) ready
    if (t + 1 < nt) { STAGE(1, kbeg + (t + 1) * 64); LOADV(vaB, (t + 1) * 64); }
    COMPUTE(&Ks[0][0], vaA);
    __syncthreads();  // all waves done reading buf0; buf1 (t+1) ready next
    if (t + 2 < nt) { STAGE(0, kbeg + (t + 2) * 64); LOADV(vaA, (t + 2) * 64); }
    if (t + 1 < nt) COMPUTE(&Ks[1][0], vaB);
  }

  // Partials out: fp32 unnormalized o + l (fixed base -> combine sums)
#pragma unroll
  for (int f = 0; f < 2; f++) {
    const int qrow = q0 + f * 16 + lq;
    const size_t sidx = ((size_t)p * 32 + bh) * SEQ + qrow;
    if (kg == 0) lP[sidx] = lac[f][0];
    float* op = oP + sidx * 32;
    *(f32x4*)(op + kg * 4) = oLo[f];
    *(f32x4*)(op + 16 + kg * 4) = oHi[f];
  }
}

// Merge 2 partial states: out = (o0+o1) / (l0+l1), write bf16
__global__ __launch_bounds__(256) void attn_combine_kernel(
    const float* __restrict__ oP, const float* __restrict__ lP,
    unsigned short* __restrict__ O) {
  const int t = blockIdx.x * blockDim.x + threadIdx.x;
  const int bh = t >> 11;
  const int qrow = t & 2047;
  const int b = bh >> 3, h = bh & 7;

  const size_t s0 = (size_t)bh * SEQ + qrow;
  const size_t s1 = ((size_t)32 + bh) * SEQ + qrow;
  const float inv = 1.f / (lP[s0] + lP[s1]);

  const float* o0 = oP + s0 * 32;
  const float* o1 = oP + s1 * 32;
  unsigned short* outp =
      O + (size_t)b * SEQ * DMODEL + (size_t)qrow * DMODEL + h * 32;
#pragma unroll
  for (int i = 0; i < 8; i++) {
    float4 a = *(const float4*)(o0 + i * 4);
    float4 c = *(const float4*)(o1 + i * 4);
    uint2 v;
    v.x = pk2((a.x + c.x) * inv, (a.y + c.y) * inv);
    v.y = pk2((a.z + c.z) * inv, (a.w + c.w) * inv);
    *(uint2*)(outp + i * 4) = v;
  }
}

// ---------------- LayerNorm of relu(P0+P1)+res (split-K combine) --------
__global__ __launch_bounds__(256) void ln_fuse_kernel(
    const float* __restrict__ P0, const float* __restrict__ P1,
    const float* __restrict__ res, const float* __restrict__ g,
    const float* __restrict__ b, float* __restrict__ Y,
    unsigned short* __restrict__ Yb) {
  const int wid = (blockIdx.x * blockDim.x + threadIdx.x) >> 6;
  const int lane = threadIdx.x & 63;
  const size_t off = (size_t)wid * DMODEL + lane * 4;
  float4 p0 = *(const float4*)(P0 + off);
  float4 p1 = *(const float4*)(P1 + off);
  float4 r = *(const float4*)(res + off);
  float4 v;
  v.x = fmaxf(p0.x + p1.x, 0.f) + r.x;
  v.y = fmaxf(p0.y + p1.y, 0.f) + r.y;
  v.z = fmaxf(p0.z + p1.z, 0.f) + r.z;
  v.w = fmaxf(p0.w + p1.w, 0.f) + r.w;
  float s = v.x + v.y + v.z + v.w;
  float s2 = v.x * v.x + v.y * v.y + v.z * v.z + v.w * v.w;
#pragma unroll
  for (int o = 32; o >= 1; o >>= 1) {
    s += __shfl_xor(s, o, 64);
    s2 += __shfl_xor(s2, o, 64);
  }
  const float mu = s * (1.f / DMODEL);
  const float var = s2 * (1.f / DMODEL) - mu * mu;
  const float inv = rsqrtf(var + LN_EPS);
  float4 gv = *(const float4*)(g + lane * 4);
  float4 bv = *(const float4*)(b + lane * 4);
  float4 o;
  o.x = (v.x - mu) * inv * gv.x + bv.x;
  o.y = (v.y - mu) * inv * gv.y + bv.y;
  o.z = (v.z - mu) * inv * gv.z + bv.z;
  o.w = (v.w - mu) * inv * gv.w + bv.w;
  if (Y) *(float4*)(Y + off) = o;
  if (Yb) {
    uint2 pk;
    pk.x = pk2(o.x, o.y);
    pk.y = pk2(o.z, o.w);
    *(uint2*)(Yb + off) = pk;
  }
}

extern "C" void kernel_launch(void* const* d_in, const int* in_sizes, int n_in,
                              void* d_out, int out_size, void* d_ws, size_t ws_size,
                              hipStream_t stream) {
  const float* x = (const float*)d_in[0];
  const float* g1 = (const float*)d_in[13];
  const float* b1 = (const float*)d_in[14];
  const float* g2 = (const float*)d_in[15];
  const float* b2 = (const float*)d_in[16];
  const float* g3 = (const float*)d_in[17];
  const float* b3 = (const float*)d_in[18];
  const float* g4 = (const float*)d_in[19];
  const float* b4 = (const float*)d_in[20];

  float* out = (float*)d_out;
  float* ws = (float*)d_ws;
  const size_t NM = (size_t)MROWS * DMODEL;
  const size_t ML = (size_t)32 * SEQ;  // 65536 rows per split
  const float QSCALE = 0.17677669529663687f * 1.4426950408889634f;

  float* F0 = ws;                       // vt alias only
  float* F1 = ws + NM;                  // fp32 residual stream
  // union [2NM,4NM): fb bf16 8192x1024 (FFN) | attn oP fp32 | o-proj P0/P1
  char* U = (char*)(ws + 2 * NM);
  unsigned short* fb = (unsigned short*)U;
  float* oP = (float*)U;
  float* oprojP0 = (float*)U;
  float* oprojP1 = (float*)U + NM;
  float* lP = ws + 4 * NM;  // 2 x 65536 fp32
  unsigned short* xb = (unsigned short*)(lP + 2 * ML);
  unsigned short* qb = xb + NM;
  unsigned short* kb = qb + NM;
  unsigned short* ob = kb + NM;
  unsigned short* nb = ob + NM;
  unsigned short* wb = nb + NM;
  unsigned short* qkv1 = wb;
  unsigned short* qkv2 = wb + 3 * 65536;
  unsigned short* o1w = wb + 6 * 65536;
  unsigned short* o2w = wb + 7 * 65536;
  unsigned short* f11 = wb + 8 * 65536;
  unsigned short* f21 = f11 + 262144;
  unsigned short* f12 = f21 + 262144;
  unsigned short* f22 = f12 + 262144;
  unsigned short* vt = (unsigned short*)F0;   // aliases F0
  float* f2P0 = (float*)qb;  // qb+kb span = NM floats (dead after attn)
  float* f2P1 = (float*)ob;  // ob+nb span = NM floats (dead after f1)

  {
    CvtArgs a;
    a.s[0] = x; a.d[0] = xb; a.n4[0] = (int)(NM / 4);
    unsigned short* wd[12] = {qkv1, qkv1 + 65536, qkv1 + 131072, o1w,
                              qkv2, qkv2 + 65536, qkv2 + 131072, o2w,
                              f11, f21, f12, f22};
    for (int i = 0; i < 12; i++) {
      a.s[i + 1] = (const float*)d_in[i + 1];
      a.d[i + 1] = wd[i];
      a.n4[i + 1] = (i < 8) ? 65536 / 4 : 262144 / 4;
    }
    cvt_kernel<<<dim3(256, 13), 256, 0, stream>>>(a);
  }

  auto gemm = [&](const unsigned short* A, const unsigned short* W,
                  unsigned short* oB, unsigned short* oB2,
                  unsigned short* oVT, float bs, int N, int K) {
    const int ntx = N / 64;
    gemm_bf16_kernel<<<ntx * (MROWS / 64), 256, 0, stream>>>(
        A, W, nullptr, nullptr, oB, oB2, oVT, nullptr, nullptr, bs, N, K,
        ntx, 0);
  };
  auto gemm_split = [&](const unsigned short* A, const unsigned short* W,
                        float* P0, float* P1, int N, int K) {
    const int ntx = N / 64;
    gemm_bf16_kernel<<<ntx * (MROWS / 64) * 2, 256, 0, stream>>>(
        A, W, nullptr, nullptr, nullptr, nullptr, nullptr, P0, P1, 1.f, N, K,
        ntx, 1);
  };
  auto attn = [&](const unsigned short* Q, const unsigned short* K,
                  const unsigned short* VT, unsigned short* O) {
    attn_mfma_kernel<<<dim3(SEQ / 128, 32, 2), 256, 0, stream>>>(
        Q, K, VT, oP, lP, SEQ / 2);
    attn_combine_kernel<<<65536 / 256, 256, 0, stream>>>(oP, lP, O);
  };
  auto ln_fuse = [&](const float* P0, const float* P1, const float* res,
                     const float* gm, const float* bt, float* Y,
                     unsigned short* Yb) {
    ln_fuse_kernel<<<MROWS / 4, 256, 0, stream>>>(P0, P1, res, gm, bt, Y, Yb);
  };

  // ---- Block 1 ----
  gemm(xb, qkv1, qb, kb, vt, QSCALE, 768, 256);        // fused QKV
  attn(qb, kb, vt, ob);                                // -> ob (bf16)
  gemm_split(ob, o1w, oprojP0, oprojP1, 256, 256);     // o-proj partials
  ln_fuse(oprojP0, oprojP1, x, g1, b1, F1, nb);        // x1n = LN(relu+x)
  gemm(nb, f11, fb, nullptr, nullptr, 1.f, 1024, 256); // f (bf16)
  gemm_split(fb, f21, f2P0, f2P1, 256, 1024);          // f2 partials
  ln_fuse(f2P0, f2P1, F1, g2, b2, F1, xb);             // block1 out

  // ---- Block 2 ----
  gemm(xb, qkv2, qb, kb, vt, QSCALE, 768, 256);
  attn(qb, kb, vt, ob);
  gemm_split(ob, o2w, oprojP0, oprojP1, 256, 256);
  ln_fuse(oprojP0, oprojP1, F1, g3, b3, F1, nb);
  gemm(nb, f12, fb, nullptr, nullptr, 1.f, 1024, 256);
  gemm_split(fb, f22, f2P0, f2P1, 256, 1024);
  ln_fuse(f2P0, f2P1, F1, g4, b4, out, nullptr);
}